// Round 6
// baseline (422.728 us; speedup 1.0000x reference)
//
#include <hip/hip_runtime.h>
#include <stdint.h>

// ---------------------------------------------------------------------------
// QuantizedLinear via int8 MFMA: y[m,n] = s_x*s_w * (xq @ wq^T)[m,n] + bias[n]
// W int8 exact; x quantized at 6/127 (clamp +-6). int32 accum exact.
//
// R8: independent-block TLP (3 blocks/CU) + read-ahead phases.
//   R5/R7 post-mortem: both schedules stuck at ~37% MfmaUtil because all
//   waves of the single resident block are barrier-locked to the same phase
//   (DS reads and MFMA serialize: sum, not max). Fix via occupancy:
//   - BM=BN=128, BK=64, 4 waves (256 thr) of 64x64 -> acc[4][4]=64 regs.
//   - LDS 3 x (8+8) KB = 48 KB -> 3 blocks/CU = 12 waves/CU (3/SIMD).
//     Independent blocks desync naturally -> one block's MFMA overlaps
//     another's reads/stages (m114: time ~ max across pipes).
//   - Phase = tile (K=64, one k-step): barrier; lgkm(0) [frags read last
//     phase done]; stage tile t+2 -> buf[(t+2)%3]; VMCNT(4) [forces t+1's
//     4 stages landed]; read tile t+1 frags -> other set; 16 MFMA on this
//     set; no trailing sync. Stage-before-wait order (R7 had wait-late).
//   - WAR: buf[(t+2)%3]=buf[(t-1)%3]; its last reads issued ph(t-2), drained
//     by lgkm(0) at ph(t-1) top, confirmed block-wide by ph(t) barrier.
//   - BK=64 XOR swizzle (4 chunks/row): LDS(r,c) holds global chunk
//     c ^ ((r>>1)&3). Bank-group(r,c) = (4r + c^((r>>1)&3)) mod 8 is
//     injective over r mod 8 -> 2 lanes/bank-group per wave read = free.
//     Staging source pre-swizzled with the same involution; LDS dest linear.
//   - NT=64 tiles: prologue (stage 0,1) + 10 x 6-phase unroll (tiles 0-59,
//     stages 2-61) + 4-phase peel (tiles 60-63, stages 62,63; VMCNT(0) only
//     at ph62). All buffer/frag-set indices static.
// ---------------------------------------------------------------------------

#define M_TOT 8192
#define N_TOT 4096
#define K_TOT 4096
#define BM 128
#define BN 128
#define BK 64               // i8 elements = 64 B per tile row = 4 x 16B chunks
#define NT (K_TOT / BK)     // 64 k-tiles

#define XCLAMP 6.0f

typedef int i32x4 __attribute__((ext_vector_type(4)));

__device__ __forceinline__ int q8(float v, float r) {
    float c = fminf(fmaxf(v * r, -127.0f), 127.0f);
    return (int)rintf(c);
}

__global__ __launch_bounds__(256) void cvt_fused(
    const float4* __restrict__ x, const int4* __restrict__ w,
    unsigned* __restrict__ xq, unsigned* __restrict__ wq, int nx4, int nw4) {
    int i = blockIdx.x * blockDim.x + threadIdx.x;
    if (i < nx4) {
        const float r = 127.0f / XCLAMP;
        float4 v = x[i];
        xq[i] = (unsigned)(q8(v.x, r) & 0xff)
              | ((unsigned)(q8(v.y, r) & 0xff) << 8)
              | ((unsigned)(q8(v.z, r) & 0xff) << 16)
              | ((unsigned)(q8(v.w, r) & 0xff) << 24);
    } else {
        int j = i - nx4;
        if (j >= nw4) return;
        int4 a = w[j];
        wq[j] = (unsigned)(a.x & 0xff)
              | ((unsigned)(a.y & 0xff) << 8)
              | ((unsigned)(a.z & 0xff) << 16)
              | ((unsigned)(a.w & 0xff) << 24);
    }
}

#define GLOAD_LDS16(gptr, lptr)                                                  \
    __builtin_amdgcn_global_load_lds(                                            \
        (const __attribute__((address_space(1))) void*)(gptr),                   \
        (__attribute__((address_space(3))) void*)(lptr), 16, 0, 0)

#define VMCNT(n) asm volatile("s_waitcnt vmcnt(" #n ")" ::: "memory")
#define NOSTG ((void)0)
#define NORD  ((void)0)

// Stage one K-tile (A:128 rows + B:128 rows, 64 B each; 2+2 wave-loads/wave).
// Wave-load slot s = wave*2+l covers LDS rows 16s..16s+15 linearly
// (gload_lds dest = uniform base + lane*16). Global source pre-swizzled:
// lane fetches row r0+(lane>>2), chunk (lane&3)^((lane>>3)&3).
#define STAGE_TILE(GA, GB, LA, LB)                                               \
    { _Pragma("unroll")                                                          \
      for (int l = 0; l < 2; ++l) {                                              \
          const int r0_ = ((wave << 1) | l) << 4;                                \
          GLOAD_LDS16((GA) + (size_t)(r0_ + srow) * K_TOT + scol,                \
                      (LA) + r0_ * BK);                                          \
      }                                                                          \
      _Pragma("unroll")                                                          \
      for (int l = 0; l < 2; ++l) {                                              \
          const int r0_ = ((wave << 1) | l) << 4;                                \
          GLOAD_LDS16((GB) + (size_t)(r0_ + srow) * K_TOT + scol,                \
                      (LB) + r0_ * BK);                                          \
      } }

// Fragment reads for one tile: 4 A + 4 B ds_read_b128 into a named set.
// Lane reads row base+(lane&15), chunk lane>>4 at swizzled pos (posr).
#define READS(DA, DB, LA, LB)                                                    \
    { _Pragma("unroll")                                                          \
      for (int i = 0; i < 4; ++i)                                                \
          DA[i] = *(const i32x4*)((LA) + (wm + i * 16 + frow) * BK + posr);      \
      _Pragma("unroll")                                                          \
      for (int j = 0; j < 4; ++j)                                                \
          DB[j] = *(const i32x4*)((LB) + (wn + j * 16 + frow) * BK + posr);      \
    }

// One phase: barrier; drain prior frag reads; stage t+2; wait t+1's stages
// (VMCNT(4)); read t+1 frags; 16 MFMA on current set.
#define PHASE(STG, CKPT, RD, SA, SB)                                             \
    {                                                                            \
        __builtin_amdgcn_s_barrier();                                            \
        asm volatile("s_waitcnt lgkmcnt(0)" ::: "memory");                       \
        __builtin_amdgcn_sched_barrier(0);                                       \
        STG;                                                                     \
        CKPT;                                                                    \
        RD;                                                                      \
        __builtin_amdgcn_sched_barrier(0);                                       \
        __builtin_amdgcn_s_setprio(1);                                           \
        _Pragma("unroll")                                                        \
        for (int i = 0; i < 4; ++i)                                              \
            _Pragma("unroll")                                                    \
            for (int j = 0; j < 4; ++j)                                          \
                acc[i][j] = __builtin_amdgcn_mfma_i32_16x16x64_i8(               \
                    SA[i], SB[j], acc[i][j], 0, 0, 0);                           \
        __builtin_amdgcn_s_setprio(0);                                           \
    }

// C = A(MxK,i8) * B(NxK,i8)^T, epilogue: out = (s_x*s_w)*acc_i32 + bias[n]
__global__ __launch_bounds__(256, 3) void gemm_i8(
    const signed char* __restrict__ A, const signed char* __restrict__ B,
    const float* __restrict__ scale, const float* __restrict__ bias,
    float* __restrict__ out) {
    __shared__ alignas(16) signed char As[3][BM * BK];  // 3 x 8 KB
    __shared__ alignas(16) signed char Bs[3][BN * BK];  // 3 x 8 KB (48 KB total)

    const int tid  = threadIdx.x;
    const int wave = tid >> 6;
    const int lane = tid & 63;
    const int bm = blockIdx.x;            // 0..63
    const int bn = blockIdx.y;            // 0..31
    const int wm = (wave >> 1) * 64;      // 2 M-waves
    const int wn = (wave & 1) * 64;       // 2 N-waves

    // frag read coords: row R = base + (lane&15), chunk c = lane>>4 at
    // LDS pos c ^ ((R>>1)&3); base mult of 16 -> xor term = (lane>>1)&3.
    const int frow = lane & 15;
    const int posr = (((lane >> 4) ^ ((lane >> 1) & 3)) << 4);
    // staging source coords (pre-swizzled global chunk)
    const int srow = lane >> 2;
    const int scol = (((lane & 3) ^ ((lane >> 3) & 3)) << 4);

    const signed char* Ag = A + (size_t)bm * BM * K_TOT;
    const signed char* Bg = B + (size_t)bn * BN * K_TOT;

    i32x4 acc[4][4] = {};
    i32x4 a0[4], b0[4], a1[4], b1[4];     // frag sets S0/S1, ping-pong

    // ---- prologue: stage tiles 0,1; wait tile0; read tile0 -> S0 ----
    STAGE_TILE(Ag, Bg, As[0], Bs[0]);
    STAGE_TILE(Ag + BK, Bg + BK, As[1], Bs[1]);
    VMCNT(4);                             // tile0's 4 landed
    __builtin_amdgcn_s_barrier();
    READS(a0, b0, As[0], Bs[0]);

    // ---- main loop: 10 iterations x 6 phases (tiles 0-59, stages 2-61) ----
#pragma unroll 1
    for (int t = 0; t < NT - 4; t += 6) {
        const signed char* A2 = Ag + (size_t)(t + 2) * BK;
        const signed char* B2 = Bg + (size_t)(t + 2) * BK;
        // ph t+0: MFMA S0 (tile t)   | stage t+2 -> b2 | reads t+1 <- b1 -> S1
        PHASE(STAGE_TILE(A2, B2, As[2], Bs[2]), VMCNT(4),
              READS(a1, b1, As[1], Bs[1]), a0, b0)
        // ph t+1: MFMA S1 (t+1)      | stage t+3 -> b0 | reads t+2 <- b2 -> S0
        PHASE(STAGE_TILE(A2 + BK, B2 + BK, As[0], Bs[0]), VMCNT(4),
              READS(a0, b0, As[2], Bs[2]), a1, b1)
        // ph t+2: MFMA S0 (t+2)      | stage t+4 -> b1 | reads t+3 <- b0 -> S1
        PHASE(STAGE_TILE(A2 + 2 * BK, B2 + 2 * BK, As[1], Bs[1]), VMCNT(4),
              READS(a1, b1, As[0], Bs[0]), a0, b0)
        // ph t+3: MFMA S1 (t+3)      | stage t+5 -> b2 | reads t+4 <- b1 -> S0
        PHASE(STAGE_TILE(A2 + 3 * BK, B2 + 3 * BK, As[2], Bs[2]), VMCNT(4),
              READS(a0, b0, As[1], Bs[1]), a1, b1)
        // ph t+4: MFMA S0 (t+4)      | stage t+6 -> b0 | reads t+5 <- b2 -> S1
        PHASE(STAGE_TILE(A2 + 4 * BK, B2 + 4 * BK, As[0], Bs[0]), VMCNT(4),
              READS(a1, b1, As[2], Bs[2]), a0, b0)
        // ph t+5: MFMA S1 (t+5)      | stage t+7 -> b1 | reads t+6 <- b0 -> S0
        PHASE(STAGE_TILE(A2 + 5 * BK, B2 + 5 * BK, As[1], Bs[1]), VMCNT(4),
              READS(a0, b0, As[0], Bs[0]), a1, b1)
    }

    // ---- peel: tiles 60(b0),61(b1),62(b2),63(b0); stage 62,63 only ----
    {
        const signed char* A62 = Ag + (size_t)62 * BK;
        const signed char* B62 = Bg + (size_t)62 * BK;
        // ph60: MFMA S0 | stage 62 -> b2 | VMCNT(4) [61 landed] | reads 61 <- b1
        PHASE(STAGE_TILE(A62, B62, As[2], Bs[2]), VMCNT(4),
              READS(a1, b1, As[1], Bs[1]), a0, b0)
        // ph61: MFMA S1 | stage 63 -> b0 | VMCNT(4) [62 landed] | reads 62 <- b2
        PHASE(STAGE_TILE(A62 + BK, B62 + BK, As[0], Bs[0]), VMCNT(4),
              READS(a0, b0, As[2], Bs[2]), a1, b1)
        // ph62: MFMA S0 | VMCNT(0) [63 landed] | reads 63 <- b0
        PHASE(NOSTG, VMCNT(0), READS(a1, b1, As[0], Bs[0]), a0, b0)
        // ph63: MFMA S1
        PHASE(NOSTG, ((void)0), NORD, a1, b1)
    }

    // epilogue: C/D layout col=lane&15, row=(lane>>4)*4+reg (dtype-independent)
    const float s = scale[0] * (XCLAMP / 127.0f);
    const int colq = lane & 15;
    const int rowq = (lane >> 4) * 4;
#pragma unroll
    for (int i = 0; i < 4; ++i) {
        const int rbase = bm * BM + wm + i * 16 + rowq;
#pragma unroll
        for (int j = 0; j < 4; ++j) {
            const int c = bn * BN + wn + j * 16 + colq;
            const float bv = bias[c];
#pragma unroll
            for (int r = 0; r < 4; ++r)
                out[(size_t)(rbase + r) * N_TOT + c] = s * (float)acc[i][j][r] + bv;
        }
    }
}

extern "C" void kernel_launch(void* const* d_in, const int* in_sizes, int n_in,
                              void* d_out, int out_size, void* d_ws, size_t ws_size,
                              hipStream_t stream) {
    const float* x     = (const float*)d_in[0];   // [8192, 4096] fp32
    const int*   w     = (const int*)d_in[1];     // [4096, 4096] int32
    const float* scale = (const float*)d_in[2];   // [1]
    const float* bias  = (const float*)d_in[3];   // [4096]
    float* out = (float*)d_out;

    signed char* Xq = (signed char*)d_ws;                           // 32 MiB
    signed char* Wq = (signed char*)d_ws + (size_t)M_TOT * K_TOT;   // +16 MiB

    const int nx4 = M_TOT * K_TOT / 4;  // 8388608
    const int nw4 = N_TOT * K_TOT / 4;  // 4194304
    const int ncvt = nx4 + nw4;
    cvt_fused<<<(ncvt + 255) / 256, 256, 0, stream>>>(
        (const float4*)x, (const int4*)w, (unsigned*)Xq, (unsigned*)Wq, nx4, nw4);

    dim3 grid(M_TOT / BM, N_TOT / BN);  // 64 x 32
    gemm_i8<<<grid, 256, 0, stream>>>(Xq, Wq, scale, bias, out);
}

// Round 7
// 410.343 us; speedup vs baseline: 1.0302x; 1.0302x over previous
//
#include <hip/hip_runtime.h>
#include <stdint.h>

// ---------------------------------------------------------------------------
// QuantizedLinear via int8 MFMA: y[m,n] = s_x*s_w * (xq @ wq^T)[m,n] + bias[n]
// W int8 exact; x quantized at 6/127 (clamp +-6). int32 accum exact.
//
// R9: LDS-byte diet. R5/R7/R8 post-mortem: phase time ~= LDS service time
// (reads+writes at ~85-128 B/cyc/CU); MFMA (653 cyc/phase) hides under it.
// Cut LDS bytes per MFMA 27% via 128x64 wave tiles + BK=64 (one 16B i8 frag
// spans the full K-tile):
//   - BM=BN=256, BK=64; 8 waves (512 thr) 2Mx4N, wave tile 128x64.
//     Per tile per wave: 12 ds_read_b128 / 32 MFMA (was 16/32), writes
//     amortized over 256^2 -> 512 B/MFMA total (was 704).
//   - acc[8][4] = 128 regs; frags aLo/aHi (in-place safe) + bA/bB ping-pong
//     = 64 regs; total ~210 -> no spill at 2 waves/SIMD (R6 lesson).
//   - 2 phases/tile, 16 MFMA each (m201 granularity), read-ahead template
//     (R6/R7/R8-verified): barrier; lgkm(0); stage/reads for NEXT phase;
//     MFMA this phase.  P0(t): MFMA lo; read aHi(t); stage t+2; VMCNT(4).
//     P1(t): MFMA hi; read aLo(t+1)+b(t+1).
//   - TRIPLE-buffered LDS 3 x 32 KB = 96 KB, 1 block/CU. WAR: stage t+2
//     -> buf[(t-1)%3], whose last reads (aHi(t-1) @P0(t-1)) drained by
//     lgkm(0) @P1(t-1), block-wide confirmed by P0(t)'s barrier.
//   - VMCNT(4): after staging t+2, outstanding = t+1's 4 + t+2's 4; wait
//     <=4 -> t+1 landed before P1(t) reads it. Never vmcnt(0) in main loop.
//   - BK=64 XOR swizzle (R8-verified, bank-conflict counter = 0):
//     LDS(r,c) holds global chunk c^((r>>1)&3); source pre-swizzled.
//   - NT=64: prologue (stage 0,1) + 10 x 6-tile unroll (tiles 0-59, stages
//     2-61) + 4-tile peel (stages 62,63; VMCNT(0) only at P0(62)).
// ---------------------------------------------------------------------------

#define M_TOT 8192
#define N_TOT 4096
#define K_TOT 4096
#define BM 256
#define BN 256
#define BK 64               // i8 elements = 64 B per tile row = 4 x 16B chunks
#define NT (K_TOT / BK)     // 64 k-tiles

#define XCLAMP 6.0f

typedef int i32x4 __attribute__((ext_vector_type(4)));

__device__ __forceinline__ int q8(float v, float r) {
    float c = fminf(fmaxf(v * r, -127.0f), 127.0f);
    return (int)rintf(c);
}

__global__ __launch_bounds__(256) void cvt_fused(
    const float4* __restrict__ x, const int4* __restrict__ w,
    unsigned* __restrict__ xq, unsigned* __restrict__ wq, int nx4, int nw4) {
    int i = blockIdx.x * blockDim.x + threadIdx.x;
    if (i < nx4) {
        const float r = 127.0f / XCLAMP;
        float4 v = x[i];
        xq[i] = (unsigned)(q8(v.x, r) & 0xff)
              | ((unsigned)(q8(v.y, r) & 0xff) << 8)
              | ((unsigned)(q8(v.z, r) & 0xff) << 16)
              | ((unsigned)(q8(v.w, r) & 0xff) << 24);
    } else {
        int j = i - nx4;
        if (j >= nw4) return;
        int4 a = w[j];
        wq[j] = (unsigned)(a.x & 0xff)
              | ((unsigned)(a.y & 0xff) << 8)
              | ((unsigned)(a.z & 0xff) << 16)
              | ((unsigned)(a.w & 0xff) << 24);
    }
}

#define GLOAD_LDS16(gptr, lptr)                                                  \
    __builtin_amdgcn_global_load_lds(                                            \
        (const __attribute__((address_space(1))) void*)(gptr),                   \
        (__attribute__((address_space(3))) void*)(lptr), 16, 0, 0)

#define VMCNT(n) asm volatile("s_waitcnt vmcnt(" #n ")" ::: "memory")
#define NOSTG ((void)0)
#define NORD  ((void)0)
#define NOCKPT ((void)0)

// Stage one K-tile (A: 256 rows + B: 256 rows, 64 B each; 2+2 wave-loads).
// Wave-load slot s = wave*2+l covers LDS rows 16s..16s+15 linearly
// (gload_lds dest = uniform base + lane*16). Global source pre-swizzled:
// lane fetches row r0+(lane>>2), chunk (lane&3)^((lane>>3)&3).
#define STAGE_TILE(GA, GB, LA, LB)                                               \
    { _Pragma("unroll")                                                          \
      for (int l = 0; l < 2; ++l) {                                              \
          const int r0_ = ((wave << 1) | l) << 4;                                \
          GLOAD_LDS16((GA) + (size_t)(r0_ + srow) * K_TOT + scol,                \
                      (LA) + r0_ * BK);                                          \
      }                                                                          \
      _Pragma("unroll")                                                          \
      for (int l = 0; l < 2; ++l) {                                              \
          const int r0_ = ((wave << 1) | l) << 4;                                \
          GLOAD_LDS16((GB) + (size_t)(r0_ + srow) * K_TOT + scol,                \
                      (LB) + r0_ * BK);                                          \
      } }

// Fragment reads (ds_read_b128): A half (4 rows-of-16) or B (4 cols-of-16).
#define READ_A4(D, LA, half)                                                     \
    { _Pragma("unroll")                                                          \
      for (int i = 0; i < 4; ++i)                                                \
          D[i] = *(const i32x4*)((LA) + (wm + (half) * 64 + i * 16 + frow) * BK  \
                                 + posr); }

#define READ_B4(D, LB)                                                           \
    { _Pragma("unroll")                                                          \
      for (int j = 0; j < 4; ++j)                                                \
          D[j] = *(const i32x4*)((LB) + (wn + j * 16 + frow) * BK + posr); }

// One phase: barrier; drain prior frag reads (completed under prior MFMA);
// issue stage + next-phase reads; 16 MFMA acc[IOFF+i][j] = ASET[i] x BSET[j].
#define PHASE(STG, CKPT, RD, ASET, BSET, IOFF)                                   \
    {                                                                            \
        __builtin_amdgcn_s_barrier();                                            \
        asm volatile("s_waitcnt lgkmcnt(0)" ::: "memory");                       \
        __builtin_amdgcn_sched_barrier(0);                                       \
        STG;                                                                     \
        CKPT;                                                                    \
        RD;                                                                      \
        __builtin_amdgcn_sched_barrier(0);                                       \
        __builtin_amdgcn_s_setprio(1);                                           \
        _Pragma("unroll")                                                        \
        for (int i = 0; i < 4; ++i)                                              \
            _Pragma("unroll")                                                    \
            for (int j = 0; j < 4; ++j)                                          \
                acc[(IOFF) + i][j] = __builtin_amdgcn_mfma_i32_16x16x64_i8(      \
                    ASET[i], BSET[j], acc[(IOFF) + i][j], 0, 0, 0);              \
        __builtin_amdgcn_s_setprio(0);                                           \
    }

// C = A(MxK,i8) * B(NxK,i8)^T, epilogue: out = (s_x*s_w)*acc_i32 + bias[n]
__global__ __launch_bounds__(512, 2) void gemm_i8(
    const signed char* __restrict__ A, const signed char* __restrict__ B,
    const float* __restrict__ scale, const float* __restrict__ bias,
    float* __restrict__ out) {
    __shared__ alignas(16) signed char As[3][BM * BK];  // 3 x 16 KB
    __shared__ alignas(16) signed char Bs[3][BN * BK];  // 3 x 16 KB (96 KB)

    const int tid  = threadIdx.x;
    const int wave = tid >> 6;
    const int lane = tid & 63;
    const int bm = blockIdx.x;            // 0..31
    const int bn = blockIdx.y;            // 0..15
    const int wm = (wave >> 2) * 128;     // 2 M-waves, tile 128 rows
    const int wn = (wave & 3) * 64;       // 4 N-waves, tile 64 cols

    // frag read coords: row R = base + (lane&15), chunk c = lane>>4 at
    // LDS pos c ^ ((R>>1)&3); base mult of 16 -> xor term = (lane>>1)&3.
    const int frow = lane & 15;
    const int posr = (((lane >> 4) ^ ((lane >> 1) & 3)) << 4);
    // staging source coords (pre-swizzled global chunk)
    const int srow = lane >> 2;
    const int scol = (((lane & 3) ^ ((lane >> 3) & 3)) << 4);

    const signed char* Ag = A + (size_t)bm * BM * K_TOT;
    const signed char* Bg = B + (size_t)bn * BN * K_TOT;

    i32x4 acc[8][4] = {};
    i32x4 aLo[4], aHi[4];   // A frags: lo used in P0, hi in P1 (in-place safe)
    i32x4 bA[4], bB[4];     // B frags: ping-pong per tile parity

    // ---- prologue: stage tiles 0,1; wait tile0; read aLo(0), b(0)->bA ----
    STAGE_TILE(Ag, Bg, As[0], Bs[0]);
    STAGE_TILE(Ag + BK, Bg + BK, As[1], Bs[1]);
    VMCNT(4);                             // tile0's 4 landed
    __builtin_amdgcn_s_barrier();
    READ_A4(aLo, As[0], 0);
    READ_B4(bA, Bs[0]);

    // ---- main loop: 10 iterations x 6 tiles x 2 phases (tiles 0-59) ----
#pragma unroll 1
    for (int t = 0; t < NT - 4; t += 6) {
        const signed char* A2 = Ag + (size_t)(t + 2) * BK;
        const signed char* B2 = Bg + (size_t)(t + 2) * BK;
        // tile t+0 (buf0, bA)
        PHASE(STAGE_TILE(A2, B2, As[2], Bs[2]), VMCNT(4),
              READ_A4(aHi, As[0], 1), aLo, bA, 0)
        PHASE(NOSTG, NOCKPT,
              READ_A4(aLo, As[1], 0); READ_B4(bB, Bs[1]), aHi, bA, 4)
        // tile t+1 (buf1, bB)
        PHASE(STAGE_TILE(A2 + BK, B2 + BK, As[0], Bs[0]), VMCNT(4),
              READ_A4(aHi, As[1], 1), aLo, bB, 0)
        PHASE(NOSTG, NOCKPT,
              READ_A4(aLo, As[2], 0); READ_B4(bA, Bs[2]), aHi, bB, 4)
        // tile t+2 (buf2, bA)
        PHASE(STAGE_TILE(A2 + 2 * BK, B2 + 2 * BK, As[1], Bs[1]), VMCNT(4),
              READ_A4(aHi, As[2], 1), aLo, bA, 0)
        PHASE(NOSTG, NOCKPT,
              READ_A4(aLo, As[0], 0); READ_B4(bB, Bs[0]), aHi, bA, 4)
        // tile t+3 (buf0, bB)
        PHASE(STAGE_TILE(A2 + 3 * BK, B2 + 3 * BK, As[2], Bs[2]), VMCNT(4),
              READ_A4(aHi, As[0], 1), aLo, bB, 0)
        PHASE(NOSTG, NOCKPT,
              READ_A4(aLo, As[1], 0); READ_B4(bA, Bs[1]), aHi, bB, 4)
        // tile t+4 (buf1, bA)
        PHASE(STAGE_TILE(A2 + 4 * BK, B2 + 4 * BK, As[0], Bs[0]), VMCNT(4),
              READ_A4(aHi, As[1], 1), aLo, bA, 0)
        PHASE(NOSTG, NOCKPT,
              READ_A4(aLo, As[2], 0); READ_B4(bB, Bs[2]), aHi, bA, 4)
        // tile t+5 (buf2, bB)
        PHASE(STAGE_TILE(A2 + 5 * BK, B2 + 5 * BK, As[1], Bs[1]), VMCNT(4),
              READ_A4(aHi, As[2], 1), aLo, bB, 0)
        PHASE(NOSTG, NOCKPT,
              READ_A4(aLo, As[0], 0); READ_B4(bA, Bs[0]), aHi, bB, 4)
    }

    // ---- peel tiles 60(b0,bA), 61(b1,bB), 62(b2,bA), 63(b0,bB) ----
    {
        const signed char* A62 = Ag + (size_t)62 * BK;
        const signed char* B62 = Bg + (size_t)62 * BK;
        PHASE(STAGE_TILE(A62, B62, As[2], Bs[2]), VMCNT(4),
              READ_A4(aHi, As[0], 1), aLo, bA, 0)                   // P0(60)
        PHASE(NOSTG, NOCKPT,
              READ_A4(aLo, As[1], 0); READ_B4(bB, Bs[1]), aHi, bA, 4) // P1(60)
        PHASE(STAGE_TILE(A62 + BK, B62 + BK, As[0], Bs[0]), VMCNT(4),
              READ_A4(aHi, As[1], 1), aLo, bB, 0)                   // P0(61)
        PHASE(NOSTG, NOCKPT,
              READ_A4(aLo, As[2], 0); READ_B4(bA, Bs[2]), aHi, bB, 4) // P1(61)
        PHASE(NOSTG, VMCNT(0),
              READ_A4(aHi, As[2], 1), aLo, bA, 0)                   // P0(62)
        PHASE(NOSTG, NOCKPT,
              READ_A4(aLo, As[0], 0); READ_B4(bB, Bs[0]), aHi, bA, 4) // P1(62)
        PHASE(NOSTG, NOCKPT,
              READ_A4(aHi, As[0], 1), aLo, bB, 0)                   // P0(63)
        PHASE(NOSTG, NOCKPT, NORD, aHi, bB, 4)                      // P1(63)
    }

    // epilogue: C/D layout col=lane&15, row=(lane>>4)*4+reg (dtype-independent)
    const float s = scale[0] * (XCLAMP / 127.0f);
    const int colq = lane & 15;
    const int rowq = (lane >> 4) * 4;
#pragma unroll
    for (int i = 0; i < 8; ++i) {
        const int rbase = bm * BM + wm + i * 16 + rowq;
#pragma unroll
        for (int j = 0; j < 4; ++j) {
            const int c = bn * BN + wn + j * 16 + colq;
            const float bv = bias[c];
#pragma unroll
            for (int r = 0; r < 4; ++r)
                out[(size_t)(rbase + r) * N_TOT + c] = s * (float)acc[i][j][r] + bv;
        }
    }
}

extern "C" void kernel_launch(void* const* d_in, const int* in_sizes, int n_in,
                              void* d_out, int out_size, void* d_ws, size_t ws_size,
                              hipStream_t stream) {
    const float* x     = (const float*)d_in[0];   // [8192, 4096] fp32
    const int*   w     = (const int*)d_in[1];     // [4096, 4096] int32
    const float* scale = (const float*)d_in[2];   // [1]
    const float* bias  = (const float*)d_in[3];   // [4096]
    float* out = (float*)d_out;

    signed char* Xq = (signed char*)d_ws;                           // 32 MiB
    signed char* Wq = (signed char*)d_ws + (size_t)M_TOT * K_TOT;   // +16 MiB

    const int nx4 = M_TOT * K_TOT / 4;  // 8388608
    const int nw4 = N_TOT * K_TOT / 4;  // 4194304
    const int ncvt = nx4 + nw4;
    cvt_fused<<<(ncvt + 255) / 256, 256, 0, stream>>>(
        (const float4*)x, (const int4*)w, (unsigned*)Xq, (unsigned*)Wq, nx4, nw4);

    dim3 grid(M_TOT / BM, N_TOT / BN);  // 32 x 16
    gemm_i8<<<grid, 512, 0, stream>>>(Xq, Wq, scale, bias, out);
}